// Round 15
// baseline (175.394 us; speedup 1.0000x reference)
//
#include <hip/hip_runtime.h>
#include <math.h>

// QueryDynamicAttention: B=16, N=1024, D=768, MU=768, R=16, DR=48
// out = (x * sigmoid(channel_att)) * sigmoid(spatial)
// Hypernet GEMM (mu @ Wg*, 226 MB streamed) is HBM-bound. Round 15:
// six k_hyper structures (incl. HW-guaranteed DMA rings) all served 2.2-2.7
// TB/s; common factor = 1 KB chunks at 147 KB stride. k_pool (sequential)
// serves 6 TB/s. This round: 4 KB contiguous chunks — block = 4 waves x 256
// contiguous cols each (1024 cols), thread = 4 cols x 16 b (acc 16 f4, no
// L2 duplication), 64 FMA per 16B load, mu on scalar pipe, K-split x4 with
// IN-PLACE quarter reduce (ws stays at 22.61 MB <= proven 22.63 budget).

#define B_  16
#define N_  1024
#define D_  768
#define MU_ 768

// ---------------------------------------------------------------------------
// k_pool: avg/max pooling partials over N (32 chunks of 32 tokens) + mu transpose
__global__ __launch_bounds__(192) void k_pool(
    const float* __restrict__ x, const float* __restrict__ mu,
    float* __restrict__ mu_t, float* __restrict__ psum, float* __restrict__ pmax)
{
    int blk = blockIdx.x;
    if (blk == 512) {  // mu_t[m][b] = mu[b][m]
        for (int e = threadIdx.x; e < MU_ * B_; e += 192) {
            int m = e >> 4, b = e & 15;
            mu_t[e] = mu[b * MU_ + m];
        }
        return;
    }
    int b = blk >> 5, c = blk & 31;
    int d4 = threadIdx.x << 2;
    const float* xp = x + ((size_t)(b * N_ + c * 32)) * D_ + d4;
    float s0 = 0.f, s1 = 0.f, s2 = 0.f, s3 = 0.f;
    float m0 = -3.4e38f, m1 = -3.4e38f, m2 = -3.4e38f, m3 = -3.4e38f;
    for (int n = 0; n < 32; ++n) {
        float4 v = *(const float4*)(xp + (size_t)n * D_);
        s0 += v.x; s1 += v.y; s2 += v.z; s3 += v.w;
        m0 = fmaxf(m0, v.x); m1 = fmaxf(m1, v.y);
        m2 = fmaxf(m2, v.z); m3 = fmaxf(m3, v.w);
    }
    size_t o = ((size_t)(c * B_ + b)) * D_ + d4;
    float4 sv = { s0, s1, s2, s3 }; *(float4*)(psum + o) = sv;
    float4 mv = { m0, m1, m2, m3 }; *(float4*)(pmax + o) = mv;
}

// ---------------------------------------------------------------------------
// k_hyper: partial[h][b][j] = sum_{m in K-quarter h} mu[b][m]*M[m][j].
// 296 blocks x 256 thr (4 waves, no LDS, no barriers). Big path: block =
// K-quarter (192 rows) x 1024 CONTIGUOUS cols (wave w owns cols
// colbase+256w .. +256(w+1)); thread = 4 cols (1 float4/row) x all 16 b.
// mu via s_load (uniform addr). 64 FMA per 16B load.
#define HFMA(MB, A0, A1, A2, A3) \
    acc[A0].x = fmaf(MB.x, wv.x, acc[A0].x); \
    acc[A0].y = fmaf(MB.x, wv.y, acc[A0].y); \
    acc[A0].z = fmaf(MB.x, wv.z, acc[A0].z); \
    acc[A0].w = fmaf(MB.x, wv.w, acc[A0].w); \
    acc[A1].x = fmaf(MB.y, wv.x, acc[A1].x); \
    acc[A1].y = fmaf(MB.y, wv.y, acc[A1].y); \
    acc[A1].z = fmaf(MB.y, wv.z, acc[A1].z); \
    acc[A1].w = fmaf(MB.y, wv.w, acc[A1].w); \
    acc[A2].x = fmaf(MB.z, wv.x, acc[A2].x); \
    acc[A2].y = fmaf(MB.z, wv.y, acc[A2].y); \
    acc[A2].z = fmaf(MB.z, wv.z, acc[A2].z); \
    acc[A2].w = fmaf(MB.z, wv.w, acc[A2].w); \
    acc[A3].x = fmaf(MB.w, wv.x, acc[A3].x); \
    acc[A3].y = fmaf(MB.w, wv.y, acc[A3].y); \
    acc[A3].z = fmaf(MB.w, wv.z, acc[A3].z); \
    acc[A3].w = fmaf(MB.w, wv.w, acc[A3].w);

__global__ __launch_bounds__(256, 2) void k_hyper(
    const float* __restrict__ Wg1, const float* __restrict__ Wg2,
    const float* __restrict__ Wgs, const float* __restrict__ Bg2,
    const float* __restrict__ mu_t,
    float* __restrict__ w1p, float* __restrict__ w2p,
    float* __restrict__ wsp, float* __restrict__ b2p)
{
    int t = blockIdx.x, tid = threadIdx.x;
    int w = tid >> 6, ln = tid & 63;

    const float* mat; float* outp; int ncols, h, colbase;
    if (t < 288) {
        int mi = t / 144; int r = t % 144;
        h = r / 36; int chunk = r % 36;
        mat = mi ? Wg2 : Wg1;
        outp = mi ? w2p : w1p;
        ncols = 36864; colbase = chunk << 10;
    } else if (t < 292) {
        h = t - 288; mat = Wgs; outp = wsp; ncols = 768; colbase = 0;
        if (w == 3) return;                 // 3 waves cover 768 cols; no barriers
    } else {
        h = t - 292; mat = Bg2; outp = b2p; ncols = 768; colbase = 0;
        if (w == 3) return;
    }
    int m0 = h * 192;
    int col = colbase + (w << 8) + (ln << 2);
    const float* p   = mat + (size_t)m0 * ncols + col;
    const float* mus = mu_t + (m0 << 4);

    float4 acc[16];
    #pragma unroll
    for (int i = 0; i < 16; ++i) acc[i] = make_float4(0.f, 0.f, 0.f, 0.f);

    #pragma unroll 4
    for (int m = 0; m < 192; ++m) {
        float4 wv = *(const float4*)p; p += ncols;          // 16 B, contiguous 4 KB/block/row
        const float4* mr = (const float4*)(mus + (m << 4)); // uniform -> s_load
        float4 u0 = mr[0], u1 = mr[1], u2 = mr[2], u3 = mr[3];
        HFMA(u0, 0, 1, 2, 3)
        HFMA(u1, 4, 5, 6, 7)
        HFMA(u2, 8, 9, 10, 11)
        HFMA(u3, 12, 13, 14, 15)
    }

    float* op = outp + (size_t)(h << 4) * ncols + col;
    #pragma unroll
    for (int b = 0; b < 16; ++b)
        *(float4*)(op + (size_t)b * ncols) = acc[b];
}

// ---------------------------------------------------------------------------
// k_redW: IN-PLACE sum of 4 K-quarter partials + bias -> quarter 0 becomes
// the final [16][ncols] array. 1176 x 256.
__global__ __launch_bounds__(256) void k_redW(
    float* __restrict__ w1p, float* __restrict__ w2p,
    float* __restrict__ wsp, float* __restrict__ b2p,
    const float* __restrict__ bg1, const float* __restrict__ bg2,
    const float* __restrict__ bgs, const float* __restrict__ bb2)
{
    int i4 = blockIdx.x * 256 + threadIdx.x;
    float* arr; const float* bias; int loc, bcols4;
    if (i4 < 147456)       { arr = w1p; bias = bg1; loc = i4;          bcols4 = 9216; }
    else if (i4 < 294912)  { arr = w2p; bias = bg2; loc = i4 - 147456; bcols4 = 9216; }
    else if (i4 < 297984)  { arr = wsp; bias = bgs; loc = i4 - 294912; bcols4 = 192; }
    else                   { arr = b2p; bias = bb2; loc = i4 - 297984; bcols4 = 192; }
    int qstride = bcols4 * 16;   // float4s per quarter
    float4 a0 = ((const float4*)arr)[loc];
    float4 a1 = ((const float4*)arr)[loc + qstride];
    float4 a2 = ((const float4*)arr)[loc + 2 * qstride];
    float4 a3 = ((const float4*)arr)[loc + 3 * qstride];
    float4 bi = ((const float4*)bias)[loc % bcols4];
    float4 o = { a0.x + a1.x + a2.x + a3.x + bi.x,
                 a0.y + a1.y + a2.y + a3.y + bi.y,
                 a0.z + a1.z + a2.z + a3.z + bi.z,
                 a0.w + a1.w + a2.w + a3.w + bi.w };
    ((float4*)arr)[loc] = o;
}

// ---------------------------------------------------------------------------
// k_red: finalize avg/max pooling (96 blocks); tile 0 also computes
// bs[b] = dot(mu[b], Bgs) + bbs.
__global__ __launch_bounds__(128) void k_red(
    const float* __restrict__ psum, const float* __restrict__ pmax,
    const float* __restrict__ mu, const float* __restrict__ Bgs,
    const float* __restrict__ bbs,
    float* __restrict__ avgb, float* __restrict__ maxb, float* __restrict__ bs)
{
    int b = blockIdx.x / 6, tile = blockIdx.x % 6, tid = threadIdx.x;
    int d = tile * 128 + tid;
    float s = 0.f, mx = -3.4e38f;
    for (int c = 0; c < 32; ++c) {
        size_t idx = ((size_t)(c * B_ + b)) * D_ + d;
        s += psum[idx];
        mx = fmaxf(mx, pmax[idx]);
    }
    avgb[b * D_ + d] = s * (1.f / 1024.f);
    maxb[b * D_ + d] = mx;

    if (tile == 0) {
        __shared__ float sb[128];
        float p = 0.f;
        for (int m = tid; m < MU_; m += 128) p += mu[b * MU_ + m] * Bgs[m];
        sb[tid] = p;
        __syncthreads();
        if (tid < 64) {
            float v = sb[tid] + sb[tid + 64];
            #pragma unroll
            for (int k = 32; k; k >>= 1) v += __shfl_xor(v, k, 64);
            if (tid == 0) bs[b] = v + bbs[0];
        }
    }
}

// ---------------------------------------------------------------------------
// k_c1: g[b][o] = relu(W1[b,o]@avg + b1) + relu(W1[b,o]@max + b1),
// b1 = dot(mu[b], Bg1[:,o]) + bb1[o] folded in. grid 768 x 64 (1 wave).
__global__ __launch_bounds__(64) void k_c1(
    const float* __restrict__ w1, const float* __restrict__ avgb,
    const float* __restrict__ maxb, const float* __restrict__ mu,
    const float* __restrict__ Bg1, const float* __restrict__ bb1,
    float* __restrict__ g)
{
    int b = blockIdx.x / 48, o = blockIdx.x % 48, ln = threadIdx.x;
    const float* row = w1 + (size_t)b * 36864 + o * 768;
    const float* av  = avgb + b * D_;
    const float* mxp = maxb + b * D_;
    const float* mub = mu + b * MU_;
    float pa = 0.f, pm = 0.f, pb = 0.f;
    #pragma unroll
    for (int i = 0; i < 12; ++i) {
        int idx = ln + (i << 6);
        float wv = row[idx];
        pa += wv * av[idx];
        pm += wv * mxp[idx];
        pb += Bg1[(size_t)idx * 48 + o] * mub[idx];
    }
    #pragma unroll
    for (int k = 32; k; k >>= 1) {
        pa += __shfl_xor(pa, k, 64);
        pm += __shfl_xor(pm, k, 64);
        pb += __shfl_xor(pb, k, 64);
    }
    if (ln == 0) {
        float bb = pb + bb1[o];
        g[b * 48 + o] = fmaxf(pa + bb, 0.f) + fmaxf(pm + bb, 0.f);
    }
}

// ---------------------------------------------------------------------------
// k_c2: att = W2[b,d,:]@g[b] + 2*b2[b,d]; cg = sigmoid(att). grid 192 x 64.
__global__ __launch_bounds__(64) void k_c2(
    const float* __restrict__ w2, const float* __restrict__ b2w,
    const float* __restrict__ g, float* __restrict__ cg)
{
    __shared__ float gL[48];
    int b = blockIdx.x / 12, tile = blockIdx.x % 12, ln = threadIdx.x;
    if (ln < 48) gL[ln] = g[b * 48 + ln];
    __syncthreads();
    int d = (tile << 6) + ln;
    const float* row = w2 + (size_t)b * 36864 + d * 48;
    float att = 0.f;
    #pragma unroll
    for (int o = 0; o < 48; o += 4) {
        float4 w4 = *(const float4*)(row + o);
        att += w4.x * gL[o] + w4.y * gL[o + 1] + w4.z * gL[o + 2] + w4.w * gL[o + 3];
    }
    att += 2.f * b2w[b * D_ + d];
    cg[b * D_ + d] = 1.f / (1.f + expf(-att));
}

// ---------------------------------------------------------------------------
// k_final: one wave per token: xg = x*cg; s = dot(xg, Ws)+bs; out = xg*sigmoid(s).
__global__ __launch_bounds__(256) void k_final(
    const float* __restrict__ x, const float* __restrict__ cg,
    const float* __restrict__ wsw, const float* __restrict__ bs,
    float* __restrict__ out)
{
    int wv = threadIdx.x >> 6, ln = threadIdx.x & 63;
    int tok = (blockIdx.x << 2) + wv;
    int b = tok >> 10;
    const float* xp = x + (size_t)tok * D_;
    const float* cp = cg + b * D_;
    const float* wp = wsw + b * D_;
    float xg[12];
    float part = 0.f;
    #pragma unroll
    for (int q = 0; q < 3; ++q) {
        int d = (q << 8) + (ln << 2);
        float4 xv = *(const float4*)(xp + d);
        float4 cv = *(const float4*)(cp + d);
        float4 w4 = *(const float4*)(wp + d);
        float g0 = xv.x * cv.x, g1 = xv.y * cv.y;
        float g2 = xv.z * cv.z, g3 = xv.w * cv.w;
        part += g0 * w4.x + g1 * w4.y + g2 * w4.z + g3 * w4.w;
        xg[q * 4 + 0] = g0; xg[q * 4 + 1] = g1;
        xg[q * 4 + 2] = g2; xg[q * 4 + 3] = g3;
    }
    #pragma unroll
    for (int k = 32; k; k >>= 1) part += __shfl_xor(part, k, 64);
    float s = part + bs[b];
    float sig = 1.f / (1.f + expf(-s));
    #pragma unroll
    for (int q = 0; q < 3; ++q) {
        int d = (q << 8) + (ln << 2);
        float4 o4 = { xg[q * 4 + 0] * sig, xg[q * 4 + 1] * sig,
                      xg[q * 4 + 2] * sig, xg[q * 4 + 3] * sig };
        *(float4*)(out + (size_t)tok * D_ + d) = o4;
    }
}

// ---------------------------------------------------------------------------
extern "C" void kernel_launch(void* const* d_in, const int* in_sizes, int n_in,
                              void* d_out, int out_size, void* d_ws, size_t ws_size,
                              hipStream_t stream)
{
    const float* x   = (const float*)d_in[0];
    const float* mu  = (const float*)d_in[1];
    const float* Wg1 = (const float*)d_in[2];
    const float* bg1 = (const float*)d_in[3];
    const float* Bg1 = (const float*)d_in[4];
    const float* bb1 = (const float*)d_in[5];
    const float* Wg2 = (const float*)d_in[6];
    const float* bg2 = (const float*)d_in[7];
    const float* Bg2 = (const float*)d_in[8];
    const float* bb2 = (const float*)d_in[9];
    const float* Wgs = (const float*)d_in[10];
    const float* bgs = (const float*)d_in[11];
    const float* Bgs = (const float*)d_in[12];
    const float* bbs = (const float*)d_in[13];
    float* base = (float*)d_ws;
    float* out  = (float*)d_out;

    // ws layout (floats); total 5,653,264 floats = 22.61 MB (<= proven 22.63)
    float* mu_t = base;                  // 12288
    float* psum = mu_t + 12288;          // 393216
    float* pmax = psum + 393216;         // 393216
    float* w1p  = pmax + 393216;         // 4*589824 (quarter 0 -> final w1)
    float* w2p  = w1p  + 2359296;        // 4*589824 (quarter 0 -> final w2)
    float* wsp  = w2p  + 2359296;        // 4*12288  (quarter 0 -> final Ws)
    float* b2p  = wsp  + 49152;          // 4*12288  (quarter 0 -> final b2)
    float* avgb = b2p  + 49152;          // 12288
    float* maxb = avgb + 12288;          // 12288
    float* g    = maxb + 12288;          // 768
    float* bs   = g    + 768;            // 16
    float* cg   = bs   + 16;             // 12288

    hipLaunchKernelGGL(k_pool,  dim3(513),  dim3(192), 0, stream, x, mu, mu_t, psum, pmax);
    hipLaunchKernelGGL(k_hyper, dim3(296),  dim3(256), 0, stream,
                       Wg1, Wg2, Wgs, Bg2, mu_t, w1p, w2p, wsp, b2p);
    hipLaunchKernelGGL(k_redW,  dim3(1176), dim3(256), 0, stream,
                       w1p, w2p, wsp, b2p, bg1, bg2, bgs, bb2);
    hipLaunchKernelGGL(k_red,   dim3(96),   dim3(128), 0, stream,
                       psum, pmax, mu, Bgs, bbs, avgb, maxb, bs);
    hipLaunchKernelGGL(k_c1,    dim3(768),  dim3(64),  0, stream,
                       w1p, avgb, maxb, mu, Bg1, bb1, g);
    hipLaunchKernelGGL(k_c2,    dim3(192),  dim3(64),  0, stream, w2p, b2p, g, cg);
    hipLaunchKernelGGL(k_final, dim3(4096), dim3(256), 0, stream, x, cg, wsp, bs, out);
}

// Round 16
// 127.544 us; speedup vs baseline: 1.3752x; 1.3752x over previous
//
#include <hip/hip_runtime.h>
#include <math.h>

// QueryDynamicAttention: B=16, N=1024, D=768, MU=768, R=16, DR=48
// out = (x * sigmoid(channel_att)) * sigmoid(spatial)
// Hypernet GEMM (mu @ Wg*, 230 MB streamed) is HBM-bound. Round 16:
// r15's 4KB-chunk test was voided by acc spill (VGPR 56 < 64 needed).
// Clean rerun: 8-wave blocks, wave = (col-quarter, b-half) -> acc[8] f4
// = 32 VGPR (no spill; launch_bounds(512,2) allows 128). Block = 1024
// contiguous cols (4 KB/row-visit), K-split x4, 296 blocks (~9.3 waves/CU),
// mu on scalar pipe, 32 FMA per 16B load, in-place quarter reduce.

#define B_  16
#define N_  1024
#define D_  768
#define MU_ 768

// ---------------------------------------------------------------------------
// k_pool: avg/max pooling partials over N (32 chunks of 32 tokens) + mu transpose
__global__ __launch_bounds__(192) void k_pool(
    const float* __restrict__ x, const float* __restrict__ mu,
    float* __restrict__ mu_t, float* __restrict__ psum, float* __restrict__ pmax)
{
    int blk = blockIdx.x;
    if (blk == 512) {  // mu_t[m][b] = mu[b][m]
        for (int e = threadIdx.x; e < MU_ * B_; e += 192) {
            int m = e >> 4, b = e & 15;
            mu_t[e] = mu[b * MU_ + m];
        }
        return;
    }
    int b = blk >> 5, c = blk & 31;
    int d4 = threadIdx.x << 2;
    const float* xp = x + ((size_t)(b * N_ + c * 32)) * D_ + d4;
    float s0 = 0.f, s1 = 0.f, s2 = 0.f, s3 = 0.f;
    float m0 = -3.4e38f, m1 = -3.4e38f, m2 = -3.4e38f, m3 = -3.4e38f;
    for (int n = 0; n < 32; ++n) {
        float4 v = *(const float4*)(xp + (size_t)n * D_);
        s0 += v.x; s1 += v.y; s2 += v.z; s3 += v.w;
        m0 = fmaxf(m0, v.x); m1 = fmaxf(m1, v.y);
        m2 = fmaxf(m2, v.z); m3 = fmaxf(m3, v.w);
    }
    size_t o = ((size_t)(c * B_ + b)) * D_ + d4;
    float4 sv = { s0, s1, s2, s3 }; *(float4*)(psum + o) = sv;
    float4 mv = { m0, m1, m2, m3 }; *(float4*)(pmax + o) = mv;
}

// ---------------------------------------------------------------------------
// k_hyper: partial[h][b][j] = sum_{m in K-quarter h} mu[b][m]*M[m][j].
// 296 blocks x 512 thr (8 waves, no LDS/barriers). Big path: block =
// K-quarter (192 rows) x 1024 CONTIGUOUS cols. Wave w: col-quarter wq=w&3
// (256 cols), b-half bh=w>>2 (8 b's). Thread: 4 cols x 8 b -> acc[8] f4
// = 32 VGPR. mu via s_load (uniform). 32 FMA per 16B load.
#define HFMA8(MB, A0, A1, A2, A3) \
    acc[A0].x = fmaf(MB.x, wv.x, acc[A0].x); \
    acc[A0].y = fmaf(MB.x, wv.y, acc[A0].y); \
    acc[A0].z = fmaf(MB.x, wv.z, acc[A0].z); \
    acc[A0].w = fmaf(MB.x, wv.w, acc[A0].w); \
    acc[A1].x = fmaf(MB.y, wv.x, acc[A1].x); \
    acc[A1].y = fmaf(MB.y, wv.y, acc[A1].y); \
    acc[A1].z = fmaf(MB.y, wv.z, acc[A1].z); \
    acc[A1].w = fmaf(MB.y, wv.w, acc[A1].w); \
    acc[A2].x = fmaf(MB.z, wv.x, acc[A2].x); \
    acc[A2].y = fmaf(MB.z, wv.y, acc[A2].y); \
    acc[A2].z = fmaf(MB.z, wv.z, acc[A2].z); \
    acc[A2].w = fmaf(MB.z, wv.w, acc[A2].w); \
    acc[A3].x = fmaf(MB.w, wv.x, acc[A3].x); \
    acc[A3].y = fmaf(MB.w, wv.y, acc[A3].y); \
    acc[A3].z = fmaf(MB.w, wv.z, acc[A3].z); \
    acc[A3].w = fmaf(MB.w, wv.w, acc[A3].w);

__global__ __launch_bounds__(512, 2) void k_hyper(
    const float* __restrict__ Wg1, const float* __restrict__ Wg2,
    const float* __restrict__ Wgs, const float* __restrict__ Bg2,
    const float* __restrict__ mu_t,
    float* __restrict__ w1p, float* __restrict__ w2p,
    float* __restrict__ wsp, float* __restrict__ b2p)
{
    int t = blockIdx.x, tid = threadIdx.x;
    int w = tid >> 6, ln = tid & 63;
    int wq = w & 3;

    const float* mat; float* outp; int ncols, h, colbase;
    if (t < 288) {
        int mi = t / 144; int r = t % 144;
        h = r / 36; int chunk = r % 36;
        mat = mi ? Wg2 : Wg1;
        outp = mi ? w2p : w1p;
        ncols = 36864; colbase = chunk << 10;
    } else if (t < 292) {
        h = t - 288; mat = Wgs; outp = wsp; ncols = 768; colbase = 0;
        if (wq == 3) return;                // 3 col-quarters cover 768 cols
    } else {
        h = t - 292; mat = Bg2; outp = b2p; ncols = 768; colbase = 0;
        if (wq == 3) return;
    }
    int m0 = h * 192;
    int col = colbase + (wq << 8) + (ln << 2);
    int bh8 = __builtin_amdgcn_readfirstlane((tid >> 8) << 3);  // b-half*8 (uniform)
    const float* p   = mat + (size_t)m0 * ncols + col;
    const float* mus = mu_t + (m0 << 4) + bh8;

    float4 acc[8];
    #pragma unroll
    for (int i = 0; i < 8; ++i) acc[i] = make_float4(0.f, 0.f, 0.f, 0.f);

    #pragma unroll 4
    for (int m = 0; m < 192; ++m) {
        float4 wv = *(const float4*)p; p += ncols;   // 16 B; 4 KB contiguous per block-row
        const float4* mr = (const float4*)(mus + (m << 4));  // uniform -> s_load
        float4 u0 = mr[0], u1 = mr[1];
        HFMA8(u0, 0, 1, 2, 3)
        HFMA8(u1, 4, 5, 6, 7)
    }

    float* op = outp + (size_t)((h << 4) + bh8) * ncols + col;
    #pragma unroll
    for (int i = 0; i < 8; ++i)
        *(float4*)(op + (size_t)i * ncols) = acc[i];
}

// ---------------------------------------------------------------------------
// k_redW: IN-PLACE sum of 4 K-quarter partials + bias -> quarter 0 becomes
// the final [16][ncols] array. 1176 x 256.
__global__ __launch_bounds__(256) void k_redW(
    float* __restrict__ w1p, float* __restrict__ w2p,
    float* __restrict__ wsp, float* __restrict__ b2p,
    const float* __restrict__ bg1, const float* __restrict__ bg2,
    const float* __restrict__ bgs, const float* __restrict__ bb2)
{
    int i4 = blockIdx.x * 256 + threadIdx.x;
    float* arr; const float* bias; int loc, bcols4;
    if (i4 < 147456)       { arr = w1p; bias = bg1; loc = i4;          bcols4 = 9216; }
    else if (i4 < 294912)  { arr = w2p; bias = bg2; loc = i4 - 147456; bcols4 = 9216; }
    else if (i4 < 297984)  { arr = wsp; bias = bgs; loc = i4 - 294912; bcols4 = 192; }
    else                   { arr = b2p; bias = bb2; loc = i4 - 297984; bcols4 = 192; }
    int qstride = bcols4 * 16;   // float4s per quarter
    float4 a0 = ((const float4*)arr)[loc];
    float4 a1 = ((const float4*)arr)[loc + qstride];
    float4 a2 = ((const float4*)arr)[loc + 2 * qstride];
    float4 a3 = ((const float4*)arr)[loc + 3 * qstride];
    float4 bi = ((const float4*)bias)[loc % bcols4];
    float4 o = { a0.x + a1.x + a2.x + a3.x + bi.x,
                 a0.y + a1.y + a2.y + a3.y + bi.y,
                 a0.z + a1.z + a2.z + a3.z + bi.z,
                 a0.w + a1.w + a2.w + a3.w + bi.w };
    ((float4*)arr)[loc] = o;
}

// ---------------------------------------------------------------------------
// k_red: finalize avg/max pooling (96 blocks); tile 0 also computes
// bs[b] = dot(mu[b], Bgs) + bbs.
__global__ __launch_bounds__(128) void k_red(
    const float* __restrict__ psum, const float* __restrict__ pmax,
    const float* __restrict__ mu, const float* __restrict__ Bgs,
    const float* __restrict__ bbs,
    float* __restrict__ avgb, float* __restrict__ maxb, float* __restrict__ bs)
{
    int b = blockIdx.x / 6, tile = blockIdx.x % 6, tid = threadIdx.x;
    int d = tile * 128 + tid;
    float s = 0.f, mx = -3.4e38f;
    for (int c = 0; c < 32; ++c) {
        size_t idx = ((size_t)(c * B_ + b)) * D_ + d;
        s += psum[idx];
        mx = fmaxf(mx, pmax[idx]);
    }
    avgb[b * D_ + d] = s * (1.f / 1024.f);
    maxb[b * D_ + d] = mx;

    if (tile == 0) {
        __shared__ float sb[128];
        float p = 0.f;
        for (int m = tid; m < MU_; m += 128) p += mu[b * MU_ + m] * Bgs[m];
        sb[tid] = p;
        __syncthreads();
        if (tid < 64) {
            float v = sb[tid] + sb[tid + 64];
            #pragma unroll
            for (int k = 32; k; k >>= 1) v += __shfl_xor(v, k, 64);
            if (tid == 0) bs[b] = v + bbs[0];
        }
    }
}

// ---------------------------------------------------------------------------
// k_c1: g[b][o] = relu(W1[b,o]@avg + b1) + relu(W1[b,o]@max + b1),
// b1 = dot(mu[b], Bg1[:,o]) + bb1[o] folded in. grid 768 x 64 (1 wave).
__global__ __launch_bounds__(64) void k_c1(
    const float* __restrict__ w1, const float* __restrict__ avgb,
    const float* __restrict__ maxb, const float* __restrict__ mu,
    const float* __restrict__ Bg1, const float* __restrict__ bb1,
    float* __restrict__ g)
{
    int b = blockIdx.x / 48, o = blockIdx.x % 48, ln = threadIdx.x;
    const float* row = w1 + (size_t)b * 36864 + o * 768;
    const float* av  = avgb + b * D_;
    const float* mxp = maxb + b * D_;
    const float* mub = mu + b * MU_;
    float pa = 0.f, pm = 0.f, pb = 0.f;
    #pragma unroll
    for (int i = 0; i < 12; ++i) {
        int idx = ln + (i << 6);
        float wv = row[idx];
        pa += wv * av[idx];
        pm += wv * mxp[idx];
        pb += Bg1[(size_t)idx * 48 + o] * mub[idx];
    }
    #pragma unroll
    for (int k = 32; k; k >>= 1) {
        pa += __shfl_xor(pa, k, 64);
        pm += __shfl_xor(pm, k, 64);
        pb += __shfl_xor(pb, k, 64);
    }
    if (ln == 0) {
        float bb = pb + bb1[o];
        g[b * 48 + o] = fmaxf(pa + bb, 0.f) + fmaxf(pm + bb, 0.f);
    }
}

// ---------------------------------------------------------------------------
// k_c2: att = W2[b,d,:]@g[b] + 2*b2[b,d]; cg = sigmoid(att). grid 192 x 64.
__global__ __launch_bounds__(64) void k_c2(
    const float* __restrict__ w2, const float* __restrict__ b2w,
    const float* __restrict__ g, float* __restrict__ cg)
{
    __shared__ float gL[48];
    int b = blockIdx.x / 12, tile = blockIdx.x % 12, ln = threadIdx.x;
    if (ln < 48) gL[ln] = g[b * 48 + ln];
    __syncthreads();
    int d = (tile << 6) + ln;
    const float* row = w2 + (size_t)b * 36864 + d * 48;
    float att = 0.f;
    #pragma unroll
    for (int o = 0; o < 48; o += 4) {
        float4 w4 = *(const float4*)(row + o);
        att += w4.x * gL[o] + w4.y * gL[o + 1] + w4.z * gL[o + 2] + w4.w * gL[o + 3];
    }
    att += 2.f * b2w[b * D_ + d];
    cg[b * D_ + d] = 1.f / (1.f + expf(-att));
}

// ---------------------------------------------------------------------------
// k_final: one wave per token: xg = x*cg; s = dot(xg, Ws)+bs; out = xg*sigmoid(s).
__global__ __launch_bounds__(256) void k_final(
    const float* __restrict__ x, const float* __restrict__ cg,
    const float* __restrict__ wsw, const float* __restrict__ bs,
    float* __restrict__ out)
{
    int wv = threadIdx.x >> 6, ln = threadIdx.x & 63;
    int tok = (blockIdx.x << 2) + wv;
    int b = tok >> 10;
    const float* xp = x + (size_t)tok * D_;
    const float* cp = cg + b * D_;
    const float* wp = wsw + b * D_;
    float xg[12];
    float part = 0.f;
    #pragma unroll
    for (int q = 0; q < 3; ++q) {
        int d = (q << 8) + (ln << 2);
        float4 xv = *(const float4*)(xp + d);
        float4 cv = *(const float4*)(cp + d);
        float4 w4 = *(const float4*)(wp + d);
        float g0 = xv.x * cv.x, g1 = xv.y * cv.y;
        float g2 = xv.z * cv.z, g3 = xv.w * cv.w;
        part += g0 * w4.x + g1 * w4.y + g2 * w4.z + g3 * w4.w;
        xg[q * 4 + 0] = g0; xg[q * 4 + 1] = g1;
        xg[q * 4 + 2] = g2; xg[q * 4 + 3] = g3;
    }
    #pragma unroll
    for (int k = 32; k; k >>= 1) part += __shfl_xor(part, k, 64);
    float s = part + bs[b];
    float sig = 1.f / (1.f + expf(-s));
    #pragma unroll
    for (int q = 0; q < 3; ++q) {
        int d = (q << 8) + (ln << 2);
        float4 o4 = { xg[q * 4 + 0] * sig, xg[q * 4 + 1] * sig,
                      xg[q * 4 + 2] * sig, xg[q * 4 + 3] * sig };
        *(float4*)(out + (size_t)tok * D_ + d) = o4;
    }
}

// ---------------------------------------------------------------------------
extern "C" void kernel_launch(void* const* d_in, const int* in_sizes, int n_in,
                              void* d_out, int out_size, void* d_ws, size_t ws_size,
                              hipStream_t stream)
{
    const float* x   = (const float*)d_in[0];
    const float* mu  = (const float*)d_in[1];
    const float* Wg1 = (const float*)d_in[2];
    const float* bg1 = (const float*)d_in[3];
    const float* Bg1 = (const float*)d_in[4];
    const float* bb1 = (const float*)d_in[5];
    const float* Wg2 = (const float*)d_in[6];
    const float* bg2 = (const float*)d_in[7];
    const float* Bg2 = (const float*)d_in[8];
    const float* bb2 = (const float*)d_in[9];
    const float* Wgs = (const float*)d_in[10];
    const float* bgs = (const float*)d_in[11];
    const float* Bgs = (const float*)d_in[12];
    const float* bbs = (const float*)d_in[13];
    float* base = (float*)d_ws;
    float* out  = (float*)d_out;

    // ws layout (floats); total 5,653,264 floats = 22.61 MB
    float* mu_t = base;                  // 12288
    float* psum = mu_t + 12288;          // 393216
    float* pmax = psum + 393216;         // 393216
    float* w1p  = pmax + 393216;         // 4*589824 (quarter 0 -> final w1)
    float* w2p  = w1p  + 2359296;        // 4*589824 (quarter 0 -> final w2)
    float* wsp  = w2p  + 2359296;        // 4*12288  (quarter 0 -> final Ws)
    float* b2p  = wsp  + 49152;          // 4*12288  (quarter 0 -> final b2)
    float* avgb = b2p  + 49152;          // 12288
    float* maxb = avgb + 12288;          // 12288
    float* g    = maxb + 12288;          // 768
    float* bs   = g    + 768;            // 16
    float* cg   = bs   + 16;             // 12288

    hipLaunchKernelGGL(k_pool,  dim3(513),  dim3(192), 0, stream, x, mu, mu_t, psum, pmax);
    hipLaunchKernelGGL(k_hyper, dim3(296),  dim3(512), 0, stream,
                       Wg1, Wg2, Wgs, Bg2, mu_t, w1p, w2p, wsp, b2p);
    hipLaunchKernelGGL(k_redW,  dim3(1176), dim3(256), 0, stream,
                       w1p, w2p, wsp, b2p, bg1, bg2, bgs, bb2);
    hipLaunchKernelGGL(k_red,   dim3(96),   dim3(128), 0, stream,
                       psum, pmax, mu, Bgs, bbs, avgb, maxb, bs);
    hipLaunchKernelGGL(k_c1,    dim3(768),  dim3(64),  0, stream,
                       w1p, avgb, maxb, mu, Bg1, bb1, g);
    hipLaunchKernelGGL(k_c2,    dim3(192),  dim3(64),  0, stream, w2p, b2p, g, cg);
    hipLaunchKernelGGL(k_final, dim3(4096), dim3(256), 0, stream, x, cg, wsp, bs, out);
}